// Round 8
// baseline (97.180 us; speedup 1.0000x reference)
//
#include <hip/hip_runtime.h>
#include <math.h>

#define T_TOK 131072
#define NCODE 512

// output layout (float32, concatenated in return order)
#define OFF_LOSS 0
#define OFF_Q    1                    // 8388608 elements
#define OFF_PERP 8388609
#define OFF_CB   8388610              // 32768 elements
#define OFF_IDX  8421378              // 131072 elements

// ws layout (bytes):
//   0      : float loss_acc
//   64     : int counts[512]
//   4096   : float cbn[512*64]      normalized codebook fp32
//   135168 : uint4 apack[8cc][4ct][3s][2h][64 lanes]  split bf16 codebook
#define CBN_OFF   4096
#define APACK_OFF 135168

typedef short bf8   __attribute__((ext_vector_type(8)));
typedef float f32x4 __attribute__((ext_vector_type(4)));

__device__ __forceinline__ unsigned short f2bf(float f) {
    unsigned u = __float_as_uint(f);
    return (unsigned short)((u + 0x7FFFu + ((u >> 16) & 1u)) >> 16);   // RNE
}
__device__ __forceinline__ float bf2f(unsigned short h) {
    return __uint_as_float(((unsigned)h) << 16);
}
union PK { unsigned short u[8]; uint4 v; };

// ---- prep: 8 blocks x 64 threads, one code per thread ----
__global__ __launch_bounds__(64) void prep_kernel(const float* __restrict__ cb,
                                                  float* __restrict__ out,
                                                  float* __restrict__ cbn,
                                                  uint4* __restrict__ apack,
                                                  int* __restrict__ counts_g,
                                                  float* __restrict__ loss_g)
{
    const int c = blockIdx.x * 64 + threadIdx.x;
    float v[64];
    float s = 0.f;
    const float4* src = (const float4*)(cb + c * 64);
    float4* rawdst = (float4*)(out + OFF_CB + c * 64);
    #pragma unroll
    for (int q = 0; q < 16; ++q) {
        float4 t = src[q];
        v[4*q] = t.x; v[4*q+1] = t.y; v[4*q+2] = t.z; v[4*q+3] = t.w;
        s = fmaf(t.x,t.x, fmaf(t.y,t.y, fmaf(t.z,t.z, fmaf(t.w,t.w, s))));
        rawdst[q] = t;                                  // raw passthrough
    }
    const float inv = 1.0f / fmaxf(sqrtf(s), 1e-12f);
    const int cc = c >> 6, ct = (c >> 4) & 3, cl = c & 15;
    const int base = (cc * 4 + ct) * 3;
    #pragma unroll
    for (int g = 0; g < 8; ++g) {                       // h = g>>2, lg = g&3
        PK ph, pm, pl;
        #pragma unroll
        for (int j = 0; j < 8; ++j) {
            float f = v[g * 8 + j] * inv;
            cbn[c * 64 + g * 8 + j] = f;
            ph.u[j] = f2bf(f);
            float r1 = f - bf2f(ph.u[j]);               // exact Dekker residual
            pm.u[j] = f2bf(r1);
            float r2 = r1 - bf2f(pm.u[j]);              // exact
            pl.u[j] = f2bf(r2);
        }
        const int h = g >> 2, lg = g & 3;
        apack[((base + 0) * 2 + h) * 64 + lg * 16 + cl] = ph.v;
        apack[((base + 1) * 2 + h) * 64 + lg * 16 + cl] = pm.v;
        apack[((base + 2) * 2 + h) * 64 + lg * 16 + cl] = pl.v;
    }
    counts_g[c] = 0;
    if (c == 0) loss_g[0] = 0.f;
}

// one (A-group G, B-split sb) pass: 4 independent chains, distance-4 re-use.
// Per-chain order (h=0 then h=1) identical to all prior passing rounds.
#define PASSG(G, sb)                                                                     \
    {                                                                                    \
        _Pragma("unroll")                                                                \
        for (int tt = 0; tt < 2; ++tt) {                                                 \
            acc0[tt] = __builtin_amdgcn_mfma_f32_16x16x32_bf16(G[0][0], bfr[sb][0][tt], acc0[tt], 0, 0, 0); \
            acc1[tt] = __builtin_amdgcn_mfma_f32_16x16x32_bf16(G[1][0], bfr[sb][0][tt], acc1[tt], 0, 0, 0); \
        }                                                                                \
        _Pragma("unroll")                                                                \
        for (int tt = 0; tt < 2; ++tt) {                                                 \
            acc0[tt] = __builtin_amdgcn_mfma_f32_16x16x32_bf16(G[0][1], bfr[sb][1][tt], acc0[tt], 0, 0, 0); \
            acc1[tt] = __builtin_amdgcn_mfma_f32_16x16x32_bf16(G[1][1], bfr[sb][1][tt], acc1[tt], 0, 0, 0); \
        }                                                                                \
    }

// load one sA-group (4 wave-coalesced b128 loads = 16 VGPR) for phase (cc, ct0)
#define LOADG(G, sA)                                                                     \
    {                                                                                    \
        _Pragma("unroll")                                                                \
        for (int c_ = 0; c_ < 2; ++c_)                                                   \
            _Pragma("unroll")                                                            \
            for (int h_ = 0; h_ < 2; ++h_)                                               \
                G[c_][h_] = ag[((((cc * 4 + ct0 + c_) * 3) + (sA)) * 2 + h_) * 64 + lane]; \
    }

__global__ __launch_bounds__(256, 2) void main_kernel(const float* __restrict__ x,
                                                      const float* __restrict__ cbn,
                                                      const uint4* __restrict__ apack,
                                                      int* __restrict__ counts_g,
                                                      float* __restrict__ loss_g,
                                                      float* __restrict__ out)
{
    __shared__ int counts_lds[NCODE];                   // only LDS in the kernel

    const int tid  = threadIdx.x;
    const int lane = tid & 63;
    const int wv   = tid >> 6;                          // 0..3
    const int lx   = lane & 15;
    const int lg   = lane >> 4;
    const int tok0 = blockIdx.x * 128;                  // 128 tokens per block
    const int wt   = wv * 32;                           // 32 tokens per wave

    counts_lds[tid] = 0; counts_lds[tid + 256] = 0;

    const bf8* ag = (const bf8*)apack;                  // L1/L2-resident (196 KB total)

    // ---- load + split own token fragments directly from global (no LDS for B) ----
    // lane owns tokens wt + tt*16 + lx (tt=0..1), dims lg*8..+8 and 32+lg*8..+8
    bf8 bfr[3][2][2];                                   // [split][h][tt] = 48 VGPR
    float inv_n[2];
    #pragma unroll
    for (int tt = 0; tt < 2; ++tt) {
        float ss = 0.f;
        const float* xr = x + (size_t)(tok0 + wt + tt * 16 + lx) * 64 + lg * 8;
        #pragma unroll
        for (int h = 0; h < 2; ++h) {
            float4 a = *(const float4*)(xr + h * 32);
            float4 b = *(const float4*)(xr + h * 32 + 4);
            float f[8] = {a.x, a.y, a.z, a.w, b.x, b.y, b.z, b.w};
            PK ph, pm, pl;
            #pragma unroll
            for (int j = 0; j < 8; ++j) {
                ss = fmaf(f[j], f[j], ss);
                ph.u[j] = f2bf(f[j]);
                float r1 = f[j] - bf2f(ph.u[j]);
                pm.u[j] = f2bf(r1);
                float r2 = r1 - bf2f(pm.u[j]);
                pl.u[j] = f2bf(r2);
            }
            bfr[0][h][tt] = *(bf8*)&ph;
            bfr[1][h][tt] = *(bf8*)&pm;
            bfr[2][h][tt] = *(bf8*)&pl;
        }
        // full |x|^2: reduce over the 4 lg-groups sharing this token column
        ss += __shfl_xor(ss, 16);
        ss += __shfl_xor(ss, 32);
        inv_n[tt] = 1.0f / fmaxf(sqrtf(ss), 1e-12f);
    }
    __syncthreads();                                    // counts_lds zeroed

    float bm[2] = {-3e38f, -3e38f};
    int   bi[2] = {0, 0};

    // NO barriers, NO LDS staging: waves desynchronized, TLP (4 blocks/CU) hides
    // load latency. A-fragments stream in 3 sA-groups (<=32 A-regs live).
    #pragma unroll 1
    for (int cc = 0; cc < 8; ++cc) {
        #pragma unroll
        for (int cp = 0; cp < 2; ++cp) {
            const int ct0 = 2 * cp;
            bf8 G2[2][2], G1[2][2], G0[2][2];           // [ct][h], 16 VGPR each
            LOADG(G2, 2)
            LOADG(G1, 1)

            f32x4 zero = {0.f, 0.f, 0.f, 0.f};
            f32x4 acc0[2] = {zero, zero};
            f32x4 acc1[2] = {zero, zero};

            // pass order small->large: lh, mm, mh, hl, hm, hh
            PASSG(G2, 0)                                // lh   (A-lo  x B-hi)
            LOADG(G0, 0)                                // G0 loads fly under mm/mh
            PASSG(G1, 1)                                // mm
            PASSG(G1, 0)                                // mh
            PASSG(G0, 2)                                // hl
            PASSG(G0, 1)                                // hm
            PASSG(G0, 0)                                // hh

            // running argmax, strictly ascending code order (first-max tie rule)
            const int cb0 = cc * 64 + ct0 * 16 + lg * 4;
            #pragma unroll
            for (int tt = 0; tt < 2; ++tt)
                #pragma unroll
                for (int j = 0; j < 4; ++j)
                    if (acc0[tt][j] > bm[tt]) { bm[tt] = acc0[tt][j]; bi[tt] = cb0 + j; }
            #pragma unroll
            for (int tt = 0; tt < 2; ++tt)
                #pragma unroll
                for (int j = 0; j < 4; ++j)
                    if (acc1[tt][j] > bm[tt]) { bm[tt] = acc1[tt][j]; bi[tt] = cb0 + 16 + j; }
        }
    }

    // ---- combine lanes {l, l^16, l^32, l^48} (same token column), min-index ties ----
    #pragma unroll
    for (int tt = 0; tt < 2; ++tt) {
        #pragma unroll
        for (int off = 16; off < 64; off <<= 1) {
            float v2 = __shfl_xor(bm[tt], off);
            int   i2 = __shfl_xor(bi[tt], off);
            if (v2 > bm[tt] || (v2 == bm[tt] && i2 < bi[tt])) { bm[tt] = v2; bi[tt] = i2; }
        }
    }

    if (lg == 0) {                                      // lanes 0-15: one per token column
        float lp = 0.f;
        #pragma unroll
        for (int tt = 0; tt < 2; ++tt) {
            atomicAdd(&counts_lds[bi[tt]], 1);
            out[OFF_IDX + tok0 + wt + tt * 16 + lx] = (float)bi[tt];
            // ||q - x_hat||^2 = 2 - 2*cos ; cos = (x . c_hat) * inv|x|
            lp += 2.f - 2.f * bm[tt] * inv_n[tt];
        }
        lp += __shfl_xor(lp, 1); lp += __shfl_xor(lp, 2);
        lp += __shfl_xor(lp, 4); lp += __shfl_xor(lp, 8);
        if (lx == 0) atomicAdd(loss_g, lp);
    }

    // ---- quantized_st rows: idx broadcast by shfl, row gather from L2-resident cbn ----
    #pragma unroll
    for (int tt = 0; tt < 2; ++tt) {
        const int b = bi[tt];
        #pragma unroll 4
        for (int i = 0; i < 16; ++i) {
            int idx = __shfl(b, i);
            out[OFF_Q + (size_t)(tok0 + wt + tt * 16 + i) * 64 + lane] = cbn[idx * 64 + lane];
        }
    }

    __syncthreads();                                    // all histogram atomics done
    int c0 = counts_lds[tid], c1 = counts_lds[tid + 256];
    if (c0) atomicAdd(&counts_g[tid], c0);
    if (c1) atomicAdd(&counts_g[tid + 256], c1);
}

__global__ __launch_bounds__(512) void fin_kernel(const int* __restrict__ counts_g,
                                                  const float* __restrict__ loss_g,
                                                  float* __restrict__ out)
{
    __shared__ double red[512];
    int t = threadIdx.x;
    float p = (float)counts_g[t] * (1.0f / (float)T_TOK);
    red[t] = (double)(p * logf(p + 1e-10f));
    __syncthreads();
    for (int s = 256; s > 0; s >>= 1) {
        if (t < s) red[t] += red[t + s];
        __syncthreads();
    }
    if (t == 0) {
        out[OFF_PERP] = expf(-(float)red[0]);
        out[OFF_LOSS] = loss_g[0] * (1.25f / ((float)T_TOK * 64.f));
    }
}

extern "C" void kernel_launch(void* const* d_in, const int* in_sizes, int n_in,
                              void* d_out, int out_size, void* d_ws, size_t ws_size,
                              hipStream_t stream)
{
    const float* x  = (const float*)d_in[0];   // [128,8,128,64] fp32
    const float* cb = (const float*)d_in[1];   // [512,64] fp32
    float* out = (float*)d_out;
    char*  ws  = (char*)d_ws;
    float* loss_g   = (float*)(ws);
    int*   counts_g = (int*)(ws + 64);
    float* cbn      = (float*)(ws + CBN_OFF);
    uint4* apack    = (uint4*)(ws + APACK_OFF);

    prep_kernel<<<8, 64, 0, stream>>>(cb, out, cbn, apack, counts_g, loss_g);
    main_kernel<<<T_TOK / 128, 256, 0, stream>>>(x, cbn, apack, counts_g, loss_g, out);
    fin_kernel<<<1, 512, 0, stream>>>(counts_g, loss_g, out);
}

// Round 9
// 96.759 us; speedup vs baseline: 1.0043x; 1.0043x over previous
//
#include <hip/hip_runtime.h>
#include <math.h>

#define T_TOK 131072
#define NCODE 512

// output layout (float32, concatenated in return order)
#define OFF_LOSS 0
#define OFF_Q    1                    // 8388608 elements
#define OFF_PERP 8388609
#define OFF_CB   8388610              // 32768 elements
#define OFF_IDX  8421378              // 131072 elements

// ws layout (bytes):
//   0      : float loss_acc
//   64     : int counts[512]
//   4096   : float cbn[512*64]      normalized codebook fp32
//   135168 : uint4 apack[8cc][4ct][3s][2h][64 lanes]  split bf16 codebook
#define CBN_OFF   4096
#define APACK_OFF 135168

typedef short bf8   __attribute__((ext_vector_type(8)));
typedef float f32x4 __attribute__((ext_vector_type(4)));

__device__ __forceinline__ unsigned short f2bf(float f) {
    unsigned u = __float_as_uint(f);
    return (unsigned short)((u + 0x7FFFu + ((u >> 16) & 1u)) >> 16);   // RNE
}
__device__ __forceinline__ float bf2f(unsigned short h) {
    return __uint_as_float(((unsigned)h) << 16);
}
union PK { unsigned short u[8]; uint4 v; };

// ---- prep: 8 blocks x 64 threads, one code per thread ----
__global__ __launch_bounds__(64) void prep_kernel(const float* __restrict__ cb,
                                                  float* __restrict__ out,
                                                  float* __restrict__ cbn,
                                                  uint4* __restrict__ apack,
                                                  int* __restrict__ counts_g,
                                                  float* __restrict__ loss_g)
{
    const int c = blockIdx.x * 64 + threadIdx.x;
    float v[64];
    float s = 0.f;
    const float4* src = (const float4*)(cb + c * 64);
    float4* rawdst = (float4*)(out + OFF_CB + c * 64);
    #pragma unroll
    for (int q = 0; q < 16; ++q) {
        float4 t = src[q];
        v[4*q] = t.x; v[4*q+1] = t.y; v[4*q+2] = t.z; v[4*q+3] = t.w;
        s = fmaf(t.x,t.x, fmaf(t.y,t.y, fmaf(t.z,t.z, fmaf(t.w,t.w, s))));
        rawdst[q] = t;                                  // raw passthrough
    }
    const float inv = 1.0f / fmaxf(sqrtf(s), 1e-12f);
    const int cc = c >> 6, ct = (c >> 4) & 3, cl = c & 15;
    const int base = (cc * 4 + ct) * 3;
    #pragma unroll
    for (int g = 0; g < 8; ++g) {                       // h = g>>2, lg = g&3
        PK ph, pm, pl;
        #pragma unroll
        for (int j = 0; j < 8; ++j) {
            float f = v[g * 8 + j] * inv;
            cbn[c * 64 + g * 8 + j] = f;
            ph.u[j] = f2bf(f);
            float r1 = f - bf2f(ph.u[j]);               // exact Dekker residual
            pm.u[j] = f2bf(r1);
            float r2 = r1 - bf2f(pm.u[j]);              // exact
            pl.u[j] = f2bf(r2);
        }
        const int h = g >> 2, lg = g & 3;
        apack[((base + 0) * 2 + h) * 64 + lg * 16 + cl] = ph.v;
        apack[((base + 1) * 2 + h) * 64 + lg * 16 + cl] = pm.v;
        apack[((base + 2) * 2 + h) * 64 + lg * 16 + cl] = pl.v;
    }
    counts_g[c] = 0;
    if (c == 0) loss_g[0] = 0.f;
}

// one (A-split sA, B-split sb) pass: 8 independent chains issued per half,
// dependent re-use distance = 8.
#define PASS(sb, sA)                                                                     \
    {                                                                                    \
        _Pragma("unroll")                                                                \
        for (int tt = 0; tt < 4; ++tt) {                                                 \
            acc0[tt] = __builtin_amdgcn_mfma_f32_16x16x32_bf16(Af[0][sA][0], bfr[sb][0][tt], acc0[tt], 0, 0, 0); \
            acc1[tt] = __builtin_amdgcn_mfma_f32_16x16x32_bf16(Af[1][sA][0], bfr[sb][0][tt], acc1[tt], 0, 0, 0); \
        }                                                                                \
        _Pragma("unroll")                                                                \
        for (int tt = 0; tt < 4; ++tt) {                                                 \
            acc0[tt] = __builtin_amdgcn_mfma_f32_16x16x32_bf16(Af[0][sA][1], bfr[sb][1][tt], acc0[tt], 0, 0, 0); \
            acc1[tt] = __builtin_amdgcn_mfma_f32_16x16x32_bf16(Af[1][sA][1], bfr[sb][1][tt], acc1[tt], 0, 0, 0); \
        }                                                                                \
    }

#define LOADAF(cc, ct0)                                                                  \
    {                                                                                    \
        _Pragma("unroll")                                                                \
        for (int c_ = 0; c_ < 2; ++c_)                                                   \
            _Pragma("unroll")                                                            \
            for (int s_ = 0; s_ < 3; ++s_)                                               \
                _Pragma("unroll")                                                        \
                for (int h_ = 0; h_ < 2; ++h_)                                           \
                    Af[c_][s_][h_] = ag[(((((cc) * 4 + (ct0) + c_) * 3) + s_) * 2 + h_) * 64 + lane]; \
    }

#define SIXPASS PASS(0, 2) PASS(1, 1) PASS(0, 1) PASS(2, 0) PASS(1, 0) PASS(0, 0)

__global__ __launch_bounds__(256, 2) void main_kernel(const float* __restrict__ x,
                                                      const float* __restrict__ cbn,
                                                      const uint4* __restrict__ apack,
                                                      int* __restrict__ counts_g,
                                                      float* __restrict__ loss_g,
                                                      float* __restrict__ out)
{
    __shared__ int counts_lds[NCODE];                   // only LDS in the kernel

    const int tid  = threadIdx.x;
    const int lane = tid & 63;
    const int wv   = tid >> 6;                          // 0..3
    const int lx   = lane & 15;
    const int lg   = lane >> 4;
    const int tok0 = blockIdx.x * 256;                  // 256 tokens per block
    const int wt   = wv * 64;                           // 64 tokens per wave

    counts_lds[tid] = 0; counts_lds[tid + 256] = 0;

    // ---- load + split own token fragments directly from global (no LDS for B) ----
    bf8 bfr[3][2][4];                                   // [split][h][tt] = 96 VGPR
    float inv_n[4];
    #pragma unroll
    for (int tt = 0; tt < 4; ++tt) {
        float ss = 0.f;
        const float* xr = x + (size_t)(tok0 + wt + tt * 16 + lx) * 64 + lg * 8;
        #pragma unroll
        for (int h = 0; h < 2; ++h) {
            float4 a = *(const float4*)(xr + h * 32);
            float4 b = *(const float4*)(xr + h * 32 + 4);
            float f[8] = {a.x, a.y, a.z, a.w, b.x, b.y, b.z, b.w};
            PK ph, pm, pl;
            #pragma unroll
            for (int j = 0; j < 8; ++j) {
                ss = fmaf(f[j], f[j], ss);
                ph.u[j] = f2bf(f[j]);
                float r1 = f[j] - bf2f(ph.u[j]);
                pm.u[j] = f2bf(r1);
                float r2 = r1 - bf2f(pm.u[j]);
                pl.u[j] = f2bf(r2);
            }
            bfr[0][h][tt] = *(bf8*)&ph;
            bfr[1][h][tt] = *(bf8*)&pm;
            bfr[2][h][tt] = *(bf8*)&pl;
        }
        ss += __shfl_xor(ss, 16);
        ss += __shfl_xor(ss, 32);
        inv_n[tt] = 1.0f / fmaxf(sqrtf(ss), 1e-12f);
    }
    __syncthreads();                                    // counts_lds zeroed

    float bm[4] = {-3e38f, -3e38f, -3e38f, -3e38f};
    int   bi[4] = {0, 0, 0, 0};

    const bf8* ag = (const bf8*)apack;                  // L1/L2-resident (196 KB total)

    #pragma unroll 2
    for (int cc = 0; cc < 8; ++cc) {
        #pragma unroll
        for (int cp = 0; cp < 2; ++cp) {
            const int ct0 = 2 * cp;
            bf8 Af[2][3][2];                            // [ct][s][h] = 48 VGPR
            LOADAF(cc, ct0)

            f32x4 zero = {0.f, 0.f, 0.f, 0.f};
            f32x4 acc0[4] = {zero, zero, zero, zero};
            f32x4 acc1[4] = {zero, zero, zero, zero};

            SIXPASS

            const int cb0 = cc * 64 + ct0 * 16 + lg * 4;
            #pragma unroll
            for (int tt = 0; tt < 4; ++tt)
                #pragma unroll
                for (int j = 0; j < 4; ++j)
                    if (acc0[tt][j] > bm[tt]) { bm[tt] = acc0[tt][j]; bi[tt] = cb0 + j; }
            #pragma unroll
            for (int tt = 0; tt < 4; ++tt)
                #pragma unroll
                for (int j = 0; j < 4; ++j)
                    if (acc1[tt][j] > bm[tt]) { bm[tt] = acc1[tt][j]; bi[tt] = cb0 + 16 + j; }
        }
    }

    #pragma unroll
    for (int tt = 0; tt < 4; ++tt) {
        #pragma unroll
        for (int off = 16; off < 64; off <<= 1) {
            float v2 = __shfl_xor(bm[tt], off);
            int   i2 = __shfl_xor(bi[tt], off);
            if (v2 > bm[tt] || (v2 == bm[tt] && i2 < bi[tt])) { bm[tt] = v2; bi[tt] = i2; }
        }
    }

    if (lg == 0) {
        float lp = 0.f;
        #pragma unroll
        for (int tt = 0; tt < 4; ++tt) {
            atomicAdd(&counts_lds[bi[tt]], 1);
            out[OFF_IDX + tok0 + wt + tt * 16 + lx] = (float)bi[tt];
            lp += 2.f - 2.f * bm[tt] * inv_n[tt];
        }
        lp += __shfl_xor(lp, 1); lp += __shfl_xor(lp, 2);
        lp += __shfl_xor(lp, 4); lp += __shfl_xor(lp, 8);
        if (lx == 0) atomicAdd(loss_g, lp);
    }

    #pragma unroll
    for (int tt = 0; tt < 4; ++tt) {
        const int b = bi[tt];
        #pragma unroll 4
        for (int i = 0; i < 16; ++i) {
            int idx = __shfl(b, i);
            out[OFF_Q + (size_t)(tok0 + wt + tt * 16 + i) * 64 + lane] = cbn[idx * 64 + lane];
        }
    }

    __syncthreads();
    int c0 = counts_lds[tid], c1 = counts_lds[tid + 256];
    if (c0) atomicAdd(&counts_g[tid], c0);
    if (c1) atomicAdd(&counts_g[tid + 256], c1);
}

// ================= DIAGNOSTIC KERNELS (4 of 16 phases, no output writes) ==========
// Results pinned live via asm volatile (rule #17) so nothing is DCE'd.

__device__ __forceinline__ void pin4(const f32x4* a, const f32x4* b) {
    float t = 0.f;
    #pragma unroll
    for (int i = 0; i < 4; ++i)
        #pragma unroll
        for (int j = 0; j < 4; ++j) t += a[i][j] + b[i][j];
    asm volatile("" :: "v"(t));
}

// MFMA-only: same wave geometry & per-phase MFMA count as main (96/phase), no memory.
__global__ __launch_bounds__(256, 2) void diag_m2()
{
    const int lane = threadIdx.x & 63;
    bf8 bfr[3][2][4];
    bf8 Af[2][3][2];
    PK p;
    #pragma unroll
    for (int s = 0; s < 3; ++s)
        #pragma unroll
        for (int h = 0; h < 2; ++h) {
            #pragma unroll
            for (int j = 0; j < 8; ++j) p.u[j] = (unsigned short)(0x3f80 + ((lane * 7 + j + s + h) & 0x3f));
            #pragma unroll
            for (int tt = 0; tt < 4; ++tt) bfr[s][h][tt] = *(bf8*)&p;
            Af[0][s][h] = *(bf8*)&p;
            Af[1][s][h] = *(bf8*)&p;
        }
    f32x4 zero = {0.f, 0.f, 0.f, 0.f};
    f32x4 acc0[4] = {zero, zero, zero, zero};
    f32x4 acc1[4] = {zero, zero, zero, zero};
    #pragma unroll 1
    for (int ph = 0; ph < 4; ++ph) {
        SIXPASS
    }
    pin4(acc0, acc1);
}

// loads + MFMA: real per-phase A-fragment loads feeding the MFMAs, no argmax.
__global__ __launch_bounds__(256, 2) void diag_l2(const uint4* __restrict__ apack)
{
    const int lane = threadIdx.x & 63;
    const bf8* ag = (const bf8*)apack;
    bf8 bfr[3][2][4];
    PK p;
    #pragma unroll
    for (int s = 0; s < 3; ++s)
        #pragma unroll
        for (int h = 0; h < 2; ++h) {
            #pragma unroll
            for (int j = 0; j < 8; ++j) p.u[j] = (unsigned short)(0x3f80 + ((lane * 7 + j + s + h) & 0x3f));
            #pragma unroll
            for (int tt = 0; tt < 4; ++tt) bfr[s][h][tt] = *(bf8*)&p;
        }
    f32x4 zero = {0.f, 0.f, 0.f, 0.f};
    f32x4 acc0[4] = {zero, zero, zero, zero};
    f32x4 acc1[4] = {zero, zero, zero, zero};
    #pragma unroll 1
    for (int ph = 0; ph < 4; ++ph) {
        const int cc = ph >> 1, ct0 = (ph & 1) * 2;
        bf8 Af[2][3][2];
        LOADAF(cc, ct0)
        SIXPASS
    }
    pin4(acc0, acc1);
}

// full phase body: loads + MFMA + running argmax (no epilogue).
__global__ __launch_bounds__(256, 2) void diag_f2(const uint4* __restrict__ apack)
{
    const int lane = threadIdx.x & 63;
    const int lg = lane >> 4;
    const bf8* ag = (const bf8*)apack;
    bf8 bfr[3][2][4];
    PK p;
    #pragma unroll
    for (int s = 0; s < 3; ++s)
        #pragma unroll
        for (int h = 0; h < 2; ++h) {
            #pragma unroll
            for (int j = 0; j < 8; ++j) p.u[j] = (unsigned short)(0x3f80 + ((lane * 7 + j + s + h) & 0x3f));
            #pragma unroll
            for (int tt = 0; tt < 4; ++tt) bfr[s][h][tt] = *(bf8*)&p;
        }
    float bm[4] = {-3e38f, -3e38f, -3e38f, -3e38f};
    int   bi[4] = {0, 0, 0, 0};
    #pragma unroll 1
    for (int ph = 0; ph < 4; ++ph) {
        const int cc = ph >> 1, ct0 = (ph & 1) * 2;
        bf8 Af[2][3][2];
        LOADAF(cc, ct0)
        f32x4 zero = {0.f, 0.f, 0.f, 0.f};
        f32x4 acc0[4] = {zero, zero, zero, zero};
        f32x4 acc1[4] = {zero, zero, zero, zero};
        SIXPASS
        const int cb0 = cc * 64 + ct0 * 16 + lg * 4;
        #pragma unroll
        for (int tt = 0; tt < 4; ++tt)
            #pragma unroll
            for (int j = 0; j < 4; ++j)
                if (acc0[tt][j] > bm[tt]) { bm[tt] = acc0[tt][j]; bi[tt] = cb0 + j; }
        #pragma unroll
        for (int tt = 0; tt < 4; ++tt)
            #pragma unroll
            for (int j = 0; j < 4; ++j)
                if (acc1[tt][j] > bm[tt]) { bm[tt] = acc1[tt][j]; bi[tt] = cb0 + 16 + j; }
    }
    asm volatile("" :: "v"(bm[0]), "v"(bm[1]), "v"(bm[2]), "v"(bm[3]),
                       "v"(bi[0]), "v"(bi[1]), "v"(bi[2]), "v"(bi[3]));
}

__global__ __launch_bounds__(512) void fin_kernel(const int* __restrict__ counts_g,
                                                  const float* __restrict__ loss_g,
                                                  float* __restrict__ out)
{
    __shared__ double red[512];
    int t = threadIdx.x;
    float p = (float)counts_g[t] * (1.0f / (float)T_TOK);
    red[t] = (double)(p * logf(p + 1e-10f));
    __syncthreads();
    for (int s = 256; s > 0; s >>= 1) {
        if (t < s) red[t] += red[t + s];
        __syncthreads();
    }
    if (t == 0) {
        out[OFF_PERP] = expf(-(float)red[0]);
        out[OFF_LOSS] = loss_g[0] * (1.25f / ((float)T_TOK * 64.f));
    }
}

extern "C" void kernel_launch(void* const* d_in, const int* in_sizes, int n_in,
                              void* d_out, int out_size, void* d_ws, size_t ws_size,
                              hipStream_t stream)
{
    const float* x  = (const float*)d_in[0];   // [128,8,128,64] fp32
    const float* cb = (const float*)d_in[1];   // [512,64] fp32
    float* out = (float*)d_out;
    char*  ws  = (char*)d_ws;
    float* loss_g   = (float*)(ws);
    int*   counts_g = (int*)(ws + 64);
    float* cbn      = (float*)(ws + CBN_OFF);
    uint4* apack    = (uint4*)(ws + APACK_OFF);

    prep_kernel<<<8, 64, 0, stream>>>(cb, out, cbn, apack, counts_g, loss_g);
    main_kernel<<<T_TOK / 256, 256, 0, stream>>>(x, cbn, apack, counts_g, loss_g, out);
    diag_m2<<<T_TOK / 256, 256, 0, stream>>>();
    diag_l2<<<T_TOK / 256, 256, 0, stream>>>(apack);
    diag_f2<<<T_TOK / 256, 256, 0, stream>>>(apack);
    fin_kernel<<<1, 512, 0, stream>>>(counts_g, loss_g, out);
}

// Round 10
// 81.060 us; speedup vs baseline: 1.1989x; 1.1937x over previous
//
#include <hip/hip_runtime.h>
#include <math.h>

#define T_TOK 131072
#define NCODE 512

// output layout (float32, concatenated in return order)
#define OFF_LOSS 0
#define OFF_Q    1                    // 8388608 elements
#define OFF_PERP 8388609
#define OFF_CB   8388610              // 32768 elements
#define OFF_IDX  8421378              // 131072 elements

// ws layout (bytes):
//   0      : float loss_acc
//   64     : int counts[512]
//   4096   : float cbn[512*64]      normalized codebook fp32
//   135168 : uint4 apack[8cc][4ct][3s][2h][64 lanes]  split bf16 codebook
#define CBN_OFF   4096
#define APACK_OFF 135168

typedef short bf8   __attribute__((ext_vector_type(8)));
typedef float f32x4 __attribute__((ext_vector_type(4)));

__device__ __forceinline__ unsigned short f2bf(float f) {
    unsigned u = __float_as_uint(f);
    return (unsigned short)((u + 0x7FFFu + ((u >> 16) & 1u)) >> 16);   // RNE
}
__device__ __forceinline__ float bf2f(unsigned short h) {
    return __uint_as_float(((unsigned)h) << 16);
}
union PK { unsigned short u[8]; uint4 v; };

// ---- prep: 8 blocks x 64 threads, one code per thread ----
__global__ __launch_bounds__(64) void prep_kernel(const float* __restrict__ cb,
                                                  float* __restrict__ out,
                                                  float* __restrict__ cbn,
                                                  uint4* __restrict__ apack,
                                                  int* __restrict__ counts_g,
                                                  float* __restrict__ loss_g)
{
    const int c = blockIdx.x * 64 + threadIdx.x;
    float v[64];
    float s = 0.f;
    const float4* src = (const float4*)(cb + c * 64);
    float4* rawdst = (float4*)(out + OFF_CB + c * 64);
    #pragma unroll
    for (int q = 0; q < 16; ++q) {
        float4 t = src[q];
        v[4*q] = t.x; v[4*q+1] = t.y; v[4*q+2] = t.z; v[4*q+3] = t.w;
        s = fmaf(t.x,t.x, fmaf(t.y,t.y, fmaf(t.z,t.z, fmaf(t.w,t.w, s))));
        rawdst[q] = t;                                  // raw passthrough
    }
    const float inv = 1.0f / fmaxf(sqrtf(s), 1e-12f);
    const int cc = c >> 6, ct = (c >> 4) & 3, cl = c & 15;
    const int base = (cc * 4 + ct) * 3;
    #pragma unroll
    for (int g = 0; g < 8; ++g) {                       // h = g>>2, lg = g&3
        PK ph, pm, pl;
        #pragma unroll
        for (int j = 0; j < 8; ++j) {
            float f = v[g * 8 + j] * inv;
            cbn[c * 64 + g * 8 + j] = f;
            ph.u[j] = f2bf(f);
            float r1 = f - bf2f(ph.u[j]);               // exact Dekker residual
            pm.u[j] = f2bf(r1);
            float r2 = r1 - bf2f(pm.u[j]);              // exact
            pl.u[j] = f2bf(r2);
        }
        const int h = g >> 2, lg = g & 3;
        apack[((base + 0) * 2 + h) * 64 + lg * 16 + cl] = ph.v;
        apack[((base + 1) * 2 + h) * 64 + lg * 16 + cl] = pm.v;
        apack[((base + 2) * 2 + h) * 64 + lg * 16 + cl] = pl.v;
    }
    counts_g[c] = 0;
    if (c == 0) loss_g[0] = 0.f;
}

// one (A-split sA, B-split sb) pass: 8 independent chains issued per half,
// dependent re-use distance = 8. Per-chain order (h=0 then h=1) identical
// to all prior passing rounds -> bit-identical accumulation.
#define PASS(sb, sA)                                                                     \
    {                                                                                    \
        _Pragma("unroll")                                                                \
        for (int tt = 0; tt < 4; ++tt) {                                                 \
            acc0[tt] = __builtin_amdgcn_mfma_f32_16x16x32_bf16(Af[0][sA][0], bfr[sb][0][tt], acc0[tt], 0, 0, 0); \
            acc1[tt] = __builtin_amdgcn_mfma_f32_16x16x32_bf16(Af[1][sA][0], bfr[sb][0][tt], acc1[tt], 0, 0, 0); \
        }                                                                                \
        _Pragma("unroll")                                                                \
        for (int tt = 0; tt < 4; ++tt) {                                                 \
            acc0[tt] = __builtin_amdgcn_mfma_f32_16x16x32_bf16(Af[0][sA][1], bfr[sb][1][tt], acc0[tt], 0, 0, 0); \
            acc1[tt] = __builtin_amdgcn_mfma_f32_16x16x32_bf16(Af[1][sA][1], bfr[sb][1][tt], acc1[tt], 0, 0, 0); \
        }                                                                                \
    }

#define LOADAF(cc, ct0)                                                                  \
    {                                                                                    \
        _Pragma("unroll")                                                                \
        for (int c_ = 0; c_ < 2; ++c_)                                                   \
            _Pragma("unroll")                                                            \
            for (int s_ = 0; s_ < 3; ++s_)                                               \
                _Pragma("unroll")                                                        \
                for (int h_ = 0; h_ < 2; ++h_)                                           \
                    Af[c_][s_][h_] = ag[(((((cc) * 4 + (ct0) + c_) * 3) + s_) * 2 + h_) * 64 + lane]; \
    }

// pass order small->large: lh, mm, mh, hl, hm, hh
#define SIXPASS PASS(0, 2) PASS(1, 1) PASS(0, 1) PASS(2, 0) PASS(1, 0) PASS(0, 0)

__global__ __launch_bounds__(256, 2) void main_kernel(const float* __restrict__ x,
                                                      const float* __restrict__ cbn,
                                                      const uint4* __restrict__ apack,
                                                      int* __restrict__ counts_g,
                                                      float* __restrict__ loss_g,
                                                      float* __restrict__ out)
{
    __shared__ int counts_lds[NCODE];                   // only LDS in the kernel

    const int tid  = threadIdx.x;
    const int lane = tid & 63;
    const int wv   = tid >> 6;                          // 0..3
    const int lx   = lane & 15;
    const int lg   = lane >> 4;
    const int tok0 = blockIdx.x * 256;                  // 256 tokens per block
    const int wt   = wv * 64;                           // 64 tokens per wave

    counts_lds[tid] = 0; counts_lds[tid + 256] = 0;

    // ---- load + split own token fragments directly from global (no LDS for B) ----
    // lane owns tokens wt + tt*16 + lx (tt=0..3), dims lg*8..+8 and 32+lg*8..+8
    bf8 bfr[3][2][4];                                   // [split][h][tt] = 96 regs
    float inv_n[4];
    #pragma unroll
    for (int tt = 0; tt < 4; ++tt) {
        float ss = 0.f;
        const float* xr = x + (size_t)(tok0 + wt + tt * 16 + lx) * 64 + lg * 8;
        #pragma unroll
        for (int h = 0; h < 2; ++h) {
            float4 a = *(const float4*)(xr + h * 32);
            float4 b = *(const float4*)(xr + h * 32 + 4);
            float f[8] = {a.x, a.y, a.z, a.w, b.x, b.y, b.z, b.w};
            PK ph, pm, pl;
            #pragma unroll
            for (int j = 0; j < 8; ++j) {
                ss = fmaf(f[j], f[j], ss);
                ph.u[j] = f2bf(f[j]);
                float r1 = f[j] - bf2f(ph.u[j]);
                pm.u[j] = f2bf(r1);
                float r2 = r1 - bf2f(pm.u[j]);
                pl.u[j] = f2bf(r2);
            }
            bfr[0][h][tt] = *(bf8*)&ph;
            bfr[1][h][tt] = *(bf8*)&pm;
            bfr[2][h][tt] = *(bf8*)&pl;
        }
        // full |x|^2: reduce over the 4 lg-groups sharing this token column
        ss += __shfl_xor(ss, 16);
        ss += __shfl_xor(ss, 32);
        inv_n[tt] = 1.0f / fmaxf(sqrtf(ss), 1e-12f);
    }
    __syncthreads();                                    // counts_lds zeroed

    float bm[4] = {-3e38f, -3e38f, -3e38f, -3e38f};
    int   bi[4] = {0, 0, 0, 0};

    const bf8* ag = (const bf8*)apack;                  // L1/L2-resident (196 KB total)

    // ONE phase per iteration (diag_f2 structure, r9 ablation: runs at MFMA-floor
    // pace). 4-phase unrolling was the regression: 4x A-fragment live ranges
    // forced phase serialization through register shuffling.
    #pragma unroll 1
    for (int ph = 0; ph < 16; ++ph) {
        const int cc = ph >> 1, ct0 = (ph & 1) * 2;
        bf8 Af[2][3][2];                                // [ct][s][h] = 48 regs
        LOADAF(cc, ct0)

        f32x4 zero = {0.f, 0.f, 0.f, 0.f};
        f32x4 acc0[4] = {zero, zero, zero, zero};
        f32x4 acc1[4] = {zero, zero, zero, zero};

        SIXPASS

        // running argmax, strictly ascending code order (first-max tie rule)
        const int cb0 = cc * 64 + ct0 * 16 + lg * 4;
        #pragma unroll
        for (int tt = 0; tt < 4; ++tt)
            #pragma unroll
            for (int j = 0; j < 4; ++j)
                if (acc0[tt][j] > bm[tt]) { bm[tt] = acc0[tt][j]; bi[tt] = cb0 + j; }
        #pragma unroll
        for (int tt = 0; tt < 4; ++tt)
            #pragma unroll
            for (int j = 0; j < 4; ++j)
                if (acc1[tt][j] > bm[tt]) { bm[tt] = acc1[tt][j]; bi[tt] = cb0 + 16 + j; }
    }

    // ---- combine lanes {l, l^16, l^32, l^48} (same token column), min-index ties ----
    #pragma unroll
    for (int tt = 0; tt < 4; ++tt) {
        #pragma unroll
        for (int off = 16; off < 64; off <<= 1) {
            float v2 = __shfl_xor(bm[tt], off);
            int   i2 = __shfl_xor(bi[tt], off);
            if (v2 > bm[tt] || (v2 == bm[tt] && i2 < bi[tt])) { bm[tt] = v2; bi[tt] = i2; }
        }
    }

    if (lg == 0) {                                      // lanes 0-15: one per token column
        float lp = 0.f;
        #pragma unroll
        for (int tt = 0; tt < 4; ++tt) {
            atomicAdd(&counts_lds[bi[tt]], 1);
            out[OFF_IDX + tok0 + wt + tt * 16 + lx] = (float)bi[tt];
            // ||q - x_hat||^2 = 2 - 2*cos ; cos = (x . c_hat) * inv|x|
            lp += 2.f - 2.f * bm[tt] * inv_n[tt];
        }
        lp += __shfl_xor(lp, 1); lp += __shfl_xor(lp, 2);
        lp += __shfl_xor(lp, 4); lp += __shfl_xor(lp, 8);
        if (lx == 0) atomicAdd(loss_g, lp);
    }

    // ---- quantized_st rows: idx broadcast by shfl, row gather from L2-resident cbn ----
    #pragma unroll
    for (int tt = 0; tt < 4; ++tt) {
        const int b = bi[tt];
        #pragma unroll 4
        for (int i = 0; i < 16; ++i) {
            int idx = __shfl(b, i);
            out[OFF_Q + (size_t)(tok0 + wt + tt * 16 + i) * 64 + lane] = cbn[idx * 64 + lane];
        }
    }

    __syncthreads();                                    // all histogram atomics done
    int c0 = counts_lds[tid], c1 = counts_lds[tid + 256];
    if (c0) atomicAdd(&counts_g[tid], c0);
    if (c1) atomicAdd(&counts_g[tid + 256], c1);
}

__global__ __launch_bounds__(512) void fin_kernel(const int* __restrict__ counts_g,
                                                  const float* __restrict__ loss_g,
                                                  float* __restrict__ out)
{
    __shared__ double red[512];
    int t = threadIdx.x;
    float p = (float)counts_g[t] * (1.0f / (float)T_TOK);
    red[t] = (double)(p * logf(p + 1e-10f));
    __syncthreads();
    for (int s = 256; s > 0; s >>= 1) {
        if (t < s) red[t] += red[t + s];
        __syncthreads();
    }
    if (t == 0) {
        out[OFF_PERP] = expf(-(float)red[0]);
        out[OFF_LOSS] = loss_g[0] * (1.25f / ((float)T_TOK * 64.f));
    }
}

extern "C" void kernel_launch(void* const* d_in, const int* in_sizes, int n_in,
                              void* d_out, int out_size, void* d_ws, size_t ws_size,
                              hipStream_t stream)
{
    const float* x  = (const float*)d_in[0];   // [128,8,128,64] fp32
    const float* cb = (const float*)d_in[1];   // [512,64] fp32
    float* out = (float*)d_out;
    char*  ws  = (char*)d_ws;
    float* loss_g   = (float*)(ws);
    int*   counts_g = (int*)(ws + 64);
    float* cbn      = (float*)(ws + CBN_OFF);
    uint4* apack    = (uint4*)(ws + APACK_OFF);

    prep_kernel<<<8, 64, 0, stream>>>(cb, out, cbn, apack, counts_g, loss_g);
    main_kernel<<<T_TOK / 256, 256, 0, stream>>>(x, cbn, apack, counts_g, loss_g, out);
    fin_kernel<<<1, 512, 0, stream>>>(counts_g, loss_g, out);
}

// Round 11
// 72.648 us; speedup vs baseline: 1.3377x; 1.1158x over previous
//
#include <hip/hip_runtime.h>
#include <math.h>

#define T_TOK 131072
#define NCODE 512

// output layout (float32, concatenated in return order)
#define OFF_LOSS 0
#define OFF_Q    1                    // 8388608 elements
#define OFF_PERP 8388609
#define OFF_CB   8388610              // 32768 elements
#define OFF_IDX  8421378              // 131072 elements

// ws layout (bytes):
//   0      : float loss_acc
//   64     : int counts[512]
//   4096   : float cbn[512*64]      normalized codebook fp32
//   135168 : uint4 apack[8cc][4ct][3s][2h][64 lanes]  split bf16 codebook
#define CBN_OFF   4096
#define APACK_OFF 135168

typedef short bf8   __attribute__((ext_vector_type(8)));
typedef float f32x4 __attribute__((ext_vector_type(4)));

__device__ __forceinline__ unsigned short f2bf(float f) {
    unsigned u = __float_as_uint(f);
    return (unsigned short)((u + 0x7FFFu + ((u >> 16) & 1u)) >> 16);   // RNE
}
__device__ __forceinline__ float bf2f(unsigned short h) {
    return __uint_as_float(((unsigned)h) << 16);
}
union PK { unsigned short u[8]; uint4 v; };

// ---- prep: 8 blocks x 64 threads, one code per thread ----
__global__ __launch_bounds__(64) void prep_kernel(const float* __restrict__ cb,
                                                  float* __restrict__ out,
                                                  float* __restrict__ cbn,
                                                  uint4* __restrict__ apack,
                                                  int* __restrict__ counts_g,
                                                  float* __restrict__ loss_g)
{
    const int c = blockIdx.x * 64 + threadIdx.x;
    float v[64];
    float s = 0.f;
    const float4* src = (const float4*)(cb + c * 64);
    float4* rawdst = (float4*)(out + OFF_CB + c * 64);
    #pragma unroll
    for (int q = 0; q < 16; ++q) {
        float4 t = src[q];
        v[4*q] = t.x; v[4*q+1] = t.y; v[4*q+2] = t.z; v[4*q+3] = t.w;
        s = fmaf(t.x,t.x, fmaf(t.y,t.y, fmaf(t.z,t.z, fmaf(t.w,t.w, s))));
        rawdst[q] = t;                                  // raw passthrough
    }
    const float inv = 1.0f / fmaxf(sqrtf(s), 1e-12f);
    const int cc = c >> 6, ct = (c >> 4) & 3, cl = c & 15;
    const int base = (cc * 4 + ct) * 3;
    #pragma unroll
    for (int g = 0; g < 8; ++g) {                       // h = g>>2, lg = g&3
        PK ph, pm, pl;
        #pragma unroll
        for (int j = 0; j < 8; ++j) {
            float f = v[g * 8 + j] * inv;
            cbn[c * 64 + g * 8 + j] = f;
            ph.u[j] = f2bf(f);
            float r1 = f - bf2f(ph.u[j]);               // exact Dekker residual
            pm.u[j] = f2bf(r1);
            float r2 = r1 - bf2f(pm.u[j]);              // exact
            pl.u[j] = f2bf(r2);
        }
        const int h = g >> 2, lg = g & 3;
        apack[((base + 0) * 2 + h) * 64 + lg * 16 + cl] = ph.v;
        apack[((base + 1) * 2 + h) * 64 + lg * 16 + cl] = pm.v;
        apack[((base + 2) * 2 + h) * 64 + lg * 16 + cl] = pl.v;
    }
    counts_g[c] = 0;
    if (c == 0) loss_g[0] = 0.f;
}

// one (A-split sA, B-split sb) pass: 8 independent chains issued per half,
// dependent re-use distance = 8. Per-chain order (h=0 then h=1) identical
// to all prior passing rounds -> bit-identical accumulation.
#define PASS(sb, sA)                                                                     \
    {                                                                                    \
        _Pragma("unroll")                                                                \
        for (int tt = 0; tt < 4; ++tt) {                                                 \
            acc0[tt] = __builtin_amdgcn_mfma_f32_16x16x32_bf16(Af[0][sA][0], bfr[sb][0][tt], acc0[tt], 0, 0, 0); \
            acc1[tt] = __builtin_amdgcn_mfma_f32_16x16x32_bf16(Af[1][sA][0], bfr[sb][0][tt], acc1[tt], 0, 0, 0); \
        }                                                                                \
        _Pragma("unroll")                                                                \
        for (int tt = 0; tt < 4; ++tt) {                                                 \
            acc0[tt] = __builtin_amdgcn_mfma_f32_16x16x32_bf16(Af[0][sA][1], bfr[sb][1][tt], acc0[tt], 0, 0, 0); \
            acc1[tt] = __builtin_amdgcn_mfma_f32_16x16x32_bf16(Af[1][sA][1], bfr[sb][1][tt], acc1[tt], 0, 0, 0); \
        }                                                                                \
    }

// issue order s = 2,1,0: pass `lh` consumes s=2 first, so first-needed loads
// are oldest in the vm queue -> compiler can start MFMAs at partial vmcnt.
#define LOADAF(cc, ct0)                                                                  \
    {                                                                                    \
        _Pragma("unroll")                                                                \
        for (int s_ = 2; s_ >= 0; --s_)                                                  \
            _Pragma("unroll")                                                            \
            for (int c_ = 0; c_ < 2; ++c_)                                               \
                _Pragma("unroll")                                                        \
                for (int h_ = 0; h_ < 2; ++h_)                                           \
                    Af[c_][s_][h_] = ag[(((((cc) * 4 + (ct0) + c_) * 3) + s_) * 2 + h_) * 64 + lane]; \
    }

// pass order small->large: lh, mm, mh, hl, hm, hh
#define SIXPASS PASS(0, 2) PASS(1, 1) PASS(0, 1) PASS(2, 0) PASS(1, 0) PASS(0, 0)

__global__ __launch_bounds__(256, 2) void main_kernel(const float* __restrict__ x,
                                                      const float* __restrict__ cbn,
                                                      const uint4* __restrict__ apack,
                                                      int* __restrict__ counts_g,
                                                      float* __restrict__ loss_g,
                                                      float* __restrict__ out)
{
    __shared__ int counts_lds[NCODE];                   // only LDS in the kernel

    const int tid  = threadIdx.x;
    const int lane = tid & 63;
    const int wv   = tid >> 6;                          // 0..3
    const int lx   = lane & 15;
    const int lg   = lane >> 4;
    const int tok0 = blockIdx.x * 256;                  // 256 tokens per block
    const int wt   = wv * 64;                           // 64 tokens per wave

    counts_lds[tid] = 0; counts_lds[tid + 256] = 0;

    // ---- load + split own token fragments directly from global (no LDS for B) ----
    // lane owns tokens wt + tt*16 + lx (tt=0..3), dims lg*8..+8 and 32+lg*8..+8
    bf8 bfr[3][2][4];                                   // [split][h][tt] = 96 regs
    float inv_n[4];
    #pragma unroll
    for (int tt = 0; tt < 4; ++tt) {
        float ss = 0.f;
        const float* xr = x + (size_t)(tok0 + wt + tt * 16 + lx) * 64 + lg * 8;
        #pragma unroll
        for (int h = 0; h < 2; ++h) {
            float4 a = *(const float4*)(xr + h * 32);
            float4 b = *(const float4*)(xr + h * 32 + 4);
            float f[8] = {a.x, a.y, a.z, a.w, b.x, b.y, b.z, b.w};
            PK ph, pm, pl;
            #pragma unroll
            for (int j = 0; j < 8; ++j) {
                ss = fmaf(f[j], f[j], ss);
                ph.u[j] = f2bf(f[j]);
                float r1 = f[j] - bf2f(ph.u[j]);
                pm.u[j] = f2bf(r1);
                float r2 = r1 - bf2f(pm.u[j]);
                pl.u[j] = f2bf(r2);
            }
            bfr[0][h][tt] = *(bf8*)&ph;
            bfr[1][h][tt] = *(bf8*)&pm;
            bfr[2][h][tt] = *(bf8*)&pl;
        }
        // full |x|^2: reduce over the 4 lg-groups sharing this token column
        ss += __shfl_xor(ss, 16);
        ss += __shfl_xor(ss, 32);
        inv_n[tt] = 1.0f / fmaxf(sqrtf(ss), 1e-12f);
    }
    // NOTE: no barrier here — waves enter the loop staggered (phase diversity
    // for setprio). The counts_lds-zeroing barrier moved to just before the
    // atomics (still orders zeroing before any atomicAdd).

    float bm[4] = {-3e38f, -3e38f, -3e38f, -3e38f};
    int   bi[4] = {0, 0, 0, 0};

    const bf8* ag = (const bf8*)apack;                  // L1/L2-resident (196 KB total)

    #pragma unroll 1
    for (int ph = 0; ph < 16; ++ph) {
        const int cc = ph >> 1, ct0 = (ph & 1) * 2;
        bf8 Af[2][3][2];                                // [ct][s][h] = 48 regs
        LOADAF(cc, ct0)

        f32x4 zero = {0.f, 0.f, 0.f, 0.f};
        f32x4 acc0[4] = {zero, zero, zero, zero};
        f32x4 acc1[4] = {zero, zero, zero, zero};

        __builtin_amdgcn_s_setprio(1);                  // T5: favor MFMA-holding wave
        SIXPASS
        __builtin_amdgcn_s_setprio(0);

        // running argmax, strictly ascending code order (first-max tie rule)
        const int cb0 = cc * 64 + ct0 * 16 + lg * 4;
        #pragma unroll
        for (int tt = 0; tt < 4; ++tt)
            #pragma unroll
            for (int j = 0; j < 4; ++j)
                if (acc0[tt][j] > bm[tt]) { bm[tt] = acc0[tt][j]; bi[tt] = cb0 + j; }
        #pragma unroll
        for (int tt = 0; tt < 4; ++tt)
            #pragma unroll
            for (int j = 0; j < 4; ++j)
                if (acc1[tt][j] > bm[tt]) { bm[tt] = acc1[tt][j]; bi[tt] = cb0 + 16 + j; }
    }

    // ---- combine lanes {l, l^16, l^32, l^48} (same token column), min-index ties ----
    #pragma unroll
    for (int tt = 0; tt < 4; ++tt) {
        #pragma unroll
        for (int off = 16; off < 64; off <<= 1) {
            float v2 = __shfl_xor(bm[tt], off);
            int   i2 = __shfl_xor(bi[tt], off);
            if (v2 > bm[tt] || (v2 == bm[tt] && i2 < bi[tt])) { bm[tt] = v2; bi[tt] = i2; }
        }
    }

    __syncthreads();                                    // counts zeroed before atomics

    if (lg == 0) {                                      // lanes 0-15: one per token column
        float lp = 0.f;
        #pragma unroll
        for (int tt = 0; tt < 4; ++tt) {
            atomicAdd(&counts_lds[bi[tt]], 1);
            out[OFF_IDX + tok0 + wt + tt * 16 + lx] = (float)bi[tt];
            // ||q - x_hat||^2 = 2 - 2*cos ; cos = (x . c_hat) * inv|x|
            lp += 2.f - 2.f * bm[tt] * inv_n[tt];
        }
        lp += __shfl_xor(lp, 1); lp += __shfl_xor(lp, 2);
        lp += __shfl_xor(lp, 4); lp += __shfl_xor(lp, 8);
        if (lx == 0) atomicAdd(loss_g, lp);
    }

    // ---- quantized_st rows: idx broadcast by shfl, row gather from L2-resident cbn ----
    #pragma unroll
    for (int tt = 0; tt < 4; ++tt) {
        const int b = bi[tt];
        #pragma unroll 4
        for (int i = 0; i < 16; ++i) {
            int idx = __shfl(b, i);
            out[OFF_Q + (size_t)(tok0 + wt + tt * 16 + i) * 64 + lane] = cbn[idx * 64 + lane];
        }
    }

    __syncthreads();                                    // all histogram atomics done
    int c0 = counts_lds[tid], c1 = counts_lds[tid + 256];
    if (c0) atomicAdd(&counts_g[tid], c0);
    if (c1) atomicAdd(&counts_g[tid + 256], c1);
}

__global__ __launch_bounds__(512) void fin_kernel(const int* __restrict__ counts_g,
                                                  const float* __restrict__ loss_g,
                                                  float* __restrict__ out)
{
    __shared__ double red[512];
    int t = threadIdx.x;
    float p = (float)counts_g[t] * (1.0f / (float)T_TOK);
    red[t] = (double)(p * logf(p + 1e-10f));
    __syncthreads();
    for (int s = 256; s > 0; s >>= 1) {
        if (t < s) red[t] += red[t + s];
        __syncthreads();
    }
    if (t == 0) {
        out[OFF_PERP] = expf(-(float)red[0]);
        out[OFF_LOSS] = loss_g[0] * (1.25f / ((float)T_TOK * 64.f));
    }
}

extern "C" void kernel_launch(void* const* d_in, const int* in_sizes, int n_in,
                              void* d_out, int out_size, void* d_ws, size_t ws_size,
                              hipStream_t stream)
{
    const float* x  = (const float*)d_in[0];   // [128,8,128,64] fp32
    const float* cb = (const float*)d_in[1];   // [512,64] fp32
    float* out = (float*)d_out;
    char*  ws  = (char*)d_ws;
    float* loss_g   = (float*)(ws);
    int*   counts_g = (int*)(ws + 64);
    float* cbn      = (float*)(ws + CBN_OFF);
    uint4* apack    = (uint4*)(ws + APACK_OFF);

    prep_kernel<<<8, 64, 0, stream>>>(cb, out, cbn, apack, counts_g, loss_g);
    main_kernel<<<T_TOK / 256, 256, 0, stream>>>(x, cbn, apack, counts_g, loss_g, out);
    fin_kernel<<<1, 512, 0, stream>>>(counts_g, loss_g, out);
}